// Round 9
// baseline (166.084 us; speedup 1.0000x reference)
//
#include <hip/hip_runtime.h>
#include <hip/hip_bf16.h>

typedef __hip_bfloat16 bf16;
typedef __attribute__((ext_vector_type(8))) short short8;   // 8 bf16 = 16B
typedef __attribute__((ext_vector_type(8))) __bf16 bf16x8;  // MFMA operand
typedef __attribute__((ext_vector_type(4))) float f32x4;    // MFMA accum
typedef __attribute__((ext_vector_type(2))) unsigned int u32x2;

#define L_CTX 2048
#define B_SZ 4
#define DM 1024
#define NH 16
#define DH 64
#define M_ROWS (L_CTX * B_SZ)  // 8192
#define SCQ 0.04508422002778011f  // (1/32) * log2(e)

__device__ __forceinline__ void load_lds16(const void* g, void* l) {
  __builtin_amdgcn_global_load_lds(
      (const __attribute__((address_space(1))) unsigned int*)g,
      (__attribute__((address_space(3))) unsigned int*)l, 16, 0, 0);
}

__device__ __forceinline__ f32x4 mfma16(short8 a, short8 b, f32x4 c) {
  return __builtin_amdgcn_mfma_f32_16x16x32_bf16(
      __builtin_bit_cast(bf16x8, a), __builtin_bit_cast(bf16x8, b), c, 0, 0, 0);
}

__device__ __forceinline__ short tobf(float x) {
  return __builtin_bit_cast(short, __float2bfloat16(x));
}

// P >= 0, never NaN/inf: round-half-up truncation (2 VALU vs ~5 for RNE trick)
__device__ __forceinline__ short tobf_rh(float x) {
  unsigned u = __builtin_bit_cast(unsigned, x);
  return (short)((u + 0x8000u) >> 16);
}

#if __has_builtin(__builtin_amdgcn_exp2f)
#define EXP2(x) __builtin_amdgcn_exp2f(x)
#else
#define EXP2(x) exp2f(x)
#endif

#if __has_builtin(__builtin_amdgcn_rcpf)
#define RCP(x) __builtin_amdgcn_rcpf(x)
#else
#define RCP(x) (1.0f / (x))
#endif

#define TRRD(d, N) \
  asm volatile("ds_read_b64_tr_b16 %0, %1 offset:" #N : "=v"(d) : "v"(va))

__device__ __forceinline__ short8 mkv(u32x2 a, u32x2 b) {
  union { unsigned u[4]; short8 s; } x;
  x.u[0] = a.x; x.u[1] = a.y; x.u[2] = b.x; x.u[3] = b.y;
  return x.s;
}

// ---------------- cast f32 -> bf16 (q,k,v + 4 weights) ----------------
__global__ void cast_all(const float* __restrict__ q, const float* __restrict__ k,
                         const float* __restrict__ v, const float* __restrict__ wq,
                         const float* __restrict__ wk, const float* __restrict__ wv,
                         const float* __restrict__ wo, bf16* __restrict__ dq,
                         bf16* __restrict__ dk, bf16* __restrict__ dv,
                         bf16* __restrict__ dwq, bf16* __restrict__ dwk,
                         bf16* __restrict__ dwv, bf16* __restrict__ dwo) {
  unsigned u = blockIdx.x * 256u + threadIdx.x;
  const float* src;
  bf16* dst;
  unsigned off;
  if (u < 3145728u) {
    unsigned which = u >> 20;
    off = u & 1048575u;
    src = which == 0 ? q : which == 1 ? k : v;
    dst = which == 0 ? dq : which == 1 ? dk : dv;
  } else {
    unsigned w = u - 3145728u;
    unsigned which = w >> 17;
    off = w & 131071u;
    src = which == 0 ? wq : which == 1 ? wk : which == 2 ? wv : wo;
    dst = which == 0 ? dwq : which == 1 ? dwk : which == 2 ? dwv : dwo;
  }
  const float4* s4 = (const float4*)src + (size_t)off * 2;
  float4 a = s4[0], b = s4[1];
  union { bf16 h[8]; short8 s; } o;
  o.h[0] = __float2bfloat16(a.x); o.h[1] = __float2bfloat16(a.y);
  o.h[2] = __float2bfloat16(a.z); o.h[3] = __float2bfloat16(a.w);
  o.h[4] = __float2bfloat16(b.x); o.h[5] = __float2bfloat16(b.y);
  o.h[6] = __float2bfloat16(b.z); o.h[7] = __float2bfloat16(b.w);
  *(short8*)(dst + (size_t)off * 8) = o.s;
}

// ---------- QKV GEMM: 256x256 tile, 8 waves, BK=32, 2-phase dbuf ----------
// Wave tile 128x64 (2m x 4n): 12 ds_read_b128 per 32 MFMA per K-step
// (half the LDS-read pressure of the 64x64-wave 128^2 tile).
// LDS 2 x (A 16KB | B 16KB) = 64KB -> 2 blocks/CU = 4 waves/SIMD:
// cross-block overlap hides the per-step vmcnt(0) drain.
// Swizzle ((row>>1)&3): 16-lane fragment reads land 2 lanes/bank (free).
__global__ __launch_bounds__(512, 2) void gemm_qkv(
    const bf16* __restrict__ Aq, const bf16* __restrict__ Ak,
    const bf16* __restrict__ Av, const bf16* __restrict__ Wq,
    const bf16* __restrict__ Wk, const bf16* __restrict__ Wv,
    const float* __restrict__ bq, const float* __restrict__ bk,
    const float* __restrict__ bv, bf16* __restrict__ Oq, bf16* __restrict__ Ok,
    bf16* __restrict__ Ov) {
  const int K = DM;
  // grid 384 = 8 XCD * 48; per XCD: z(0..2) x 4 M-panels x 4 N-tiles
  int bid = blockIdx.x;
  int xcd = bid & 7, t_ = bid >> 3;         // t_ in [0,48)
  int z = t_ >> 4, rem = t_ & 15;           // z in [0,3)
  int bx = rem & 3, by = xcd * 4 + (rem >> 2);  // bx N-tile, by M-tile
  const bf16* A = z == 0 ? Aq : z == 1 ? Ak : Av;
  const bf16* W = z == 0 ? Wq : z == 1 ? Wk : Wv;
  const float* bias = z == 0 ? bq : z == 1 ? bk : bv;
  bf16* Cout = z == 0 ? Oq : z == 1 ? Ok : Ov;
  const float scale = z == 0 ? SCQ : 1.0f;

  const int tid = threadIdx.x;
  const int wid = tid >> 6, ln = tid & 63, g = ln >> 4, lc = ln & 15;
  const int wm = wid >> 2, wn = wid & 3;    // 2m x 4n wave grid
  const int bm = by * 256, bn = bx * 256;

  __shared__ char smem[65536];  // 2 x (A[256][32]bf16 16KB | B 16KB)

  f32x4 acc[8][4] = {};

  // staging: 4 loads/thread/K-step; loads 0-1 -> A, 2-3 -> B.
  // idx in [0,1024) per matrix: rowi = idx>>2, chunk = idx&3;
  // source chunk pre-swizzled so LDS linear dest + XOR read is bank-clean.
  auto stage = [&](int t, int s) {
    int kk = t * 32;
#pragma unroll
    for (int l = 0; l < 4; ++l) {
      int idx = (l & 1) * 512 + tid;        // within-matrix slot
      int rowi = idx >> 2, chunk = idx & 3;
      int cs = chunk ^ ((rowi >> 1) & 3);
      char* dst = smem + s * 32768 + (l >> 1) * 16384 + (l & 1) * 8192 +
                  wid * 1024 + ln * 16;
      if (l < 2)
        load_lds16(A + (size_t)(bm + rowi) * K + kk + cs * 8, dst);
      else
        load_lds16(W + (size_t)(bn + rowi) * K + kk + cs * 8, dst);
    }
  };

  stage(0, 0);
  asm volatile("s_waitcnt vmcnt(0)" ::: "memory");
  __syncthreads();

  for (int t = 0; t < 32; ++t) {
    if (t + 1 < 32) stage(t + 1, (t + 1) & 1);
    const char* As = smem + (t & 1) * 32768;
    const char* Bs = As + 16384;
    short8 af[8], bfr[4];
#pragma unroll
    for (int m = 0; m < 8; ++m) {
      int row = wm * 128 + m * 16 + lc;
      af[m] = *(const short8*)(As + row * 64 + ((g ^ ((row >> 1) & 3)) << 4));
    }
#pragma unroll
    for (int n = 0; n < 4; ++n) {
      int row = wn * 64 + n * 16 + lc;
      bfr[n] = *(const short8*)(Bs + row * 64 + ((g ^ ((row >> 1) & 3)) << 4));
    }
    __builtin_amdgcn_s_setprio(1);
#pragma unroll
    for (int m = 0; m < 8; ++m)
#pragma unroll
      for (int n = 0; n < 4; ++n) acc[m][n] = mfma16(af[m], bfr[n], acc[m][n]);
    __builtin_amdgcn_s_setprio(0);
    asm volatile("s_waitcnt vmcnt(0)" ::: "memory");
    __syncthreads();
  }

  // epilogue: per-head layout [b][h][l][64]
#pragma unroll
  for (int n = 0; n < 4; ++n) {
    int col = bn + wn * 64 + n * 16 + lc;
    float bv = bias[col];
    int h = col >> 6, d = col & 63;
#pragma unroll
    for (int m = 0; m < 8; ++m) {
      int row0 = bm + wm * 128 + m * 16 + g * 4;
#pragma unroll
      for (int i = 0; i < 4; ++i) {
        int row = row0 + i;
        int l = row >> 2, b = row & 3;
        Cout[(((size_t)(b * NH + h)) * L_CTX + l) * DH + d] =
            __float2bfloat16((acc[m][n][i] + bv) * scale);
      }
    }
  }
}

// ---------------- gemm_out: proven 128^2 body (swizzle fixed) ----------------
__global__ __launch_bounds__(256, 3) void gemm_out(const bf16* __restrict__ A,
                                                   const bf16* __restrict__ Bw,
                                                   const float* __restrict__ bias,
                                                   float* __restrict__ Cout) {
  const int K = DM, N = DM;
  int bid = blockIdx.x;
  int xcd = bid & 7, t_ = bid >> 3;
  int u = t_ >> 3, bxi = t_ & 7;
  int byi = xcd * 8 + u;
  const int tid = threadIdx.x;
  const int wv = tid >> 6, ln = tid & 63, g = ln >> 4, lc = ln & 15;
  const int wr = wv >> 1, wc = wv & 1;
  const int bm = byi * 128, bn = bxi * 128;

  __shared__ char smem[49152];  // 3 x (As 8KB | Bs 8KB)

  f32x4 acc[4][4] = {};

  const int srow = tid >> 2, sc_ = tid & 3;
  auto stage = [&](int t, int s) {
    int kk = t * 32;
#pragma unroll
    for (int i = 0; i < 2; ++i) {
      int row = i * 64 + srow;
      int cs = sc_ ^ ((row >> 1) & 3);  // corrected swizzle
      load_lds16(A + (size_t)(bm + row) * K + kk + cs * 8,
                 smem + s * 16384 + i * 4096 + wv * 1024);
      load_lds16(Bw + (size_t)(bn + row) * K + kk + cs * 8,
                 smem + s * 16384 + 8192 + i * 4096 + wv * 1024);
    }
  };

  stage(0, 0);
  stage(1, 1);
  asm volatile("s_waitcnt vmcnt(4)" ::: "memory");
  __syncthreads();

#pragma unroll
  for (int t = 0; t < 32; ++t) {
    if (t + 2 < 32) stage(t + 2, (t + 2) % 3);
    const char* As = smem + (t % 3) * 16384;
    const char* Bs = As + 8192;
    short8 af[4], bfr[4];
#pragma unroll
    for (int m = 0; m < 4; ++m) {
      int row = wr * 64 + m * 16 + lc;
      af[m] = *(const short8*)(As + row * 64 + ((g ^ ((row >> 1) & 3)) << 4));
    }
#pragma unroll
    for (int n = 0; n < 4; ++n) {
      int row = wc * 64 + n * 16 + lc;
      bfr[n] = *(const short8*)(Bs + row * 64 + ((g ^ ((row >> 1) & 3)) << 4));
    }
    __builtin_amdgcn_s_setprio(1);
#pragma unroll
    for (int m = 0; m < 4; ++m)
#pragma unroll
      for (int n = 0; n < 4; ++n) acc[m][n] = mfma16(af[m], bfr[n], acc[m][n]);
    __builtin_amdgcn_s_setprio(0);
    if (t + 2 < 32)
      asm volatile("s_waitcnt vmcnt(4)" ::: "memory");
    else
      asm volatile("s_waitcnt vmcnt(0)" ::: "memory");
    __syncthreads();
  }

#pragma unroll
  for (int n = 0; n < 4; ++n) {
    int col = bn + wc * 64 + n * 16 + lc;
    float bv = bias[col];
#pragma unroll
    for (int m = 0; m < 4; ++m) {
      int row0 = bm + wr * 64 + m * 16 + g * 4;
#pragma unroll
      for (int i = 0; i < 4; ++i) {
        int row = row0 + i;
        Cout[(size_t)row * N + col] = acc[m][n][i] + bv;
      }
    }
  }
}

// ---------------- flash attention v7 (unchanged, proven) ----------------
__global__ __launch_bounds__(256, 4) void attn_fwd7(const bf16* __restrict__ Q,
                                                    const bf16* __restrict__ K,
                                                    const bf16* __restrict__ V,
                                                    bf16* __restrict__ O) {
  const int tid = threadIdx.x, w = tid >> 6, ln = tid & 63, g = ln >> 4,
            lc = ln & 15;
  const int bid = blockIdx.x;
  const int j = bid >> 3;
  const int bh = (bid & 7) * 8 + (j & 7);  // 8 heads per XCD -> K/V L2-local
  const int pa = j >> 3;
  const int b = bh >> 4, h = bh & 15;

  __shared__ char smem[32768];  // K 2x8KB @0, V 2x8KB @16384
  const bf16* Qh = Q + (size_t)bh * L_CTX * DH;
  const bf16* Kh = K + (size_t)bh * L_CTX * DH;
  const bf16* Vh = V + (size_t)bh * L_CTX * DH;

  const unsigned vbase =
      (unsigned)(size_t)(__attribute__((address_space(3))) char*)(smem + 16384);

  const int krow_l = ln >> 3, kslot = ln & 7;
  const int vr = (ln & 7) >> 1, vc0 = (ln & 1) * 8;

  const short ONEBF = 0x3F80;  // bf16 1.0
  const short8 ones8 = {ONEBF, ONEBF, ONEBF, ONEBF, ONEBF, ONEBF, ONEBF, ONEBF};

#pragma unroll 1
  for (int rep = 0; rep < 2; ++rep) {
    const int qt = rep ? (31 - pa) : pa;
    const int qb = qt * 64 + w * 16;
    const int nt = qt + 1;

    short8 qf0 = *(const short8*)(Qh + (qb + lc) * DH + g * 8);
    short8 qf1 = *(const short8*)(Qh + (qb + lc) * DH + 32 + g * 8);

    f32x4 oacc[4] = {};
    f32x4 lacc = {};  // rowsum accumulator

    auto stage = [&](int t, int s) {
#pragma unroll
      for (int i = 0; i < 2; ++i) {  // K: 64 rows x 128B, source-swizzled
        int row = (i * 4 + w) * 8 + krow_l;
        int slot = kslot ^ (row & 7);
        load_lds16(Kh + (size_t)(t * 64 + row) * DH + slot * 8,
                   smem + s * 8192 + (i * 4 + w) * 1024);
      }
#pragma unroll
      for (int Lg = 0; Lg < 2; ++Lg) {  // V: subtiled perm via source addr
        int blk = w * 8 + Lg * 32 + krow_l;
        int sq = blk & 15, dt = blk >> 4;
        load_lds16(Vh + (size_t)(t * 64 + sq * 4 + vr) * DH + dt * 16 + vc0,
                   smem + 16384 + s * 8192 + Lg * 4096 + w * 1024);
      }
    };

    int sel = 0;
    stage(0, 0);
    asm volatile("s_waitcnt vmcnt(0)" ::: "memory");
    __syncthreads();

    for (int t = 0; t < nt; ++t) {
      if (t + 1 < nt) stage(t + 1, sel ^ 1);

      // ---- QK^T (swapped: S^T = K*Qscaled) ----
      const char* Kl = smem + sel * 8192;
      f32x4 st[4] = {};
      __builtin_amdgcn_s_setprio(1);
#pragma unroll
      for (int tt = 0; tt < 4; ++tt) {
        int row = tt * 16 + lc, sw = lc & 7;
        short8 kf0 = *(const short8*)(Kl + row * 128 + ((g ^ sw) << 4));
        short8 kf1 = *(const short8*)(Kl + row * 128 + (((4 + g) ^ sw) << 4));
        st[tt] = mfma16(kf0, qf0, st[tt]);
        st[tt] = mfma16(kf1, qf1, st[tt]);
      }
      __builtin_amdgcn_s_setprio(0);

      // ---- issue V transpose reads early ----
      unsigned va = vbase + sel * 8192 + ln * 8;
      u32x2 t0a, t0b, t1a, t1b, t2a, t2b, t3a, t3b;
      u32x2 s0a, s0b, s1a, s1b, s2a, s2b, s3a, s3b;
      TRRD(t0a, 0);    TRRD(t0b, 512);
      TRRD(t1a, 2048); TRRD(t1b, 2560);
      TRRD(t2a, 4096); TRRD(t2b, 4608);
      TRRD(t3a, 6144); TRRD(t3b, 6656);
      TRRD(s0a, 1024); TRRD(s0b, 1536);
      TRRD(s1a, 3072); TRRD(s1b, 3584);
      TRRD(s2a, 5120); TRRD(s2b, 5632);
      TRRD(s3a, 7168); TRRD(s3b, 7680);

      // ---- causal mask: only last tile touches the diagonal ----
      if (t == nt - 1) {
        int qrel = w * 16 + lc;
#pragma unroll
        for (int tt = 0; tt < 4; ++tt)
#pragma unroll
          for (int i = 0; i < 4; ++i)
            if (tt * 16 + g * 4 + i > qrel) st[tt][i] = -__builtin_inff();
      }

      // ---- P = exp2(z) single-inst, pack round-half-up ----
      union { short s[8]; short8 v; } p0, p1;
#pragma unroll
      for (int i = 0; i < 4; ++i) {
        p0.s[i]     = tobf_rh(EXP2(st[0][i]));
        p0.s[4 + i] = tobf_rh(EXP2(st[1][i]));
        p1.s[i]     = tobf_rh(EXP2(st[2][i]));
        p1.s[4 + i] = tobf_rh(EXP2(st[3][i]));
      }

      // ---- PV + rowsum-by-MFMA ----
      asm volatile("s_waitcnt lgkmcnt(0)" ::: "memory");
      __builtin_amdgcn_sched_barrier(0);
      __builtin_amdgcn_s_setprio(1);
      oacc[0] = mfma16(p0.v, mkv(t0a, t0b), oacc[0]);
      oacc[1] = mfma16(p0.v, mkv(t1a, t1b), oacc[1]);
      oacc[2] = mfma16(p0.v, mkv(t2a, t2b), oacc[2]);
      oacc[3] = mfma16(p0.v, mkv(t3a, t3b), oacc[3]);
      lacc = mfma16(p0.v, ones8, lacc);
      oacc[0] = mfma16(p1.v, mkv(s0a, s0b), oacc[0]);
      oacc[1] = mfma16(p1.v, mkv(s1a, s1b), oacc[1]);
      oacc[2] = mfma16(p1.v, mkv(s2a, s2b), oacc[2]);
      oacc[3] = mfma16(p1.v, mkv(s3a, s3b), oacc[3]);
      lacc = mfma16(p1.v, ones8, lacc);
      __builtin_amdgcn_s_setprio(0);

      asm volatile("s_waitcnt vmcnt(0)" ::: "memory");
      __syncthreads();
      sel ^= 1;
    }

    // ---- epilogue ----
    float li[4];
#pragma unroll
    for (int i = 0; i < 4; ++i) li[i] = RCP(lacc[i]);
#pragma unroll
    for (int n = 0; n < 4; ++n)
#pragma unroll
      for (int i = 0; i < 4; ++i) {
        int qi = qb + g * 4 + i;
        int col = h * DH + n * 16 + lc;
        O[((size_t)qi * B_SZ + b) * DM + col] =
            __float2bfloat16(oacc[n][i] * li[i]);
      }
  }
}

// ---------------- launch ----------------
extern "C" void kernel_launch(void* const* d_in, const int* in_sizes, int n_in,
                              void* d_out, int out_size, void* d_ws, size_t ws_size,
                              hipStream_t stream) {
  const float* q = (const float*)d_in[0];
  const float* k = (const float*)d_in[1];
  const float* v = (const float*)d_in[2];
  const float* wq = (const float*)d_in[4];
  const float* bq = (const float*)d_in[5];
  const float* wk = (const float*)d_in[6];
  const float* bk = (const float*)d_in[7];
  const float* wv = (const float*)d_in[8];
  const float* bv = (const float*)d_in[9];
  const float* wo = (const float*)d_in[10];
  const float* bo = (const float*)d_in[11];

  if (ws_size < 125829120u) return;

  char* ws = (char*)d_ws;
  bf16* qb_ = (bf16*)(ws);
  bf16* kb_ = (bf16*)(ws + 16777216);
  bf16* vb_ = (bf16*)(ws + 33554432);
  bf16* wqb = (bf16*)(ws + 50331648);
  bf16* wkb = (bf16*)(ws + 52428800);
  bf16* wvb = (bf16*)(ws + 54525952);
  bf16* wob = (bf16*)(ws + 56623104);
  bf16* Qp = (bf16*)(ws + 58720256);
  bf16* Kp = (bf16*)(ws + 75497472);
  bf16* Vp = (bf16*)(ws + 92274688);
  bf16* Ob = (bf16*)(ws + 109051904);

  cast_all<<<14336, 256, 0, stream>>>(q, k, v, wq, wk, wv, wo, qb_, kb_, vb_, wqb,
                                      wkb, wvb, wob);
  gemm_qkv<<<384, 512, 0, stream>>>(qb_, kb_, vb_, wqb, wkb, wvb, bq, bk, bv,
                                    Qp, Kp, Vp);
  attn_fwd7<<<1024, 256, 0, stream>>>(Qp, Kp, Vp, Ob);
  gemm_out<<<512, 256, 0, stream>>>(Ob, wob, bo, (float*)d_out);
}

// Round 10
// 155.334 us; speedup vs baseline: 1.0692x; 1.0692x over previous
//
#include <hip/hip_runtime.h>
#include <hip/hip_bf16.h>

typedef __hip_bfloat16 bf16;
typedef __attribute__((ext_vector_type(8))) short short8;   // 8 bf16 = 16B
typedef __attribute__((ext_vector_type(8))) __bf16 bf16x8;  // MFMA operand
typedef __attribute__((ext_vector_type(4))) float f32x4;    // MFMA accum
typedef __attribute__((ext_vector_type(2))) unsigned int u32x2;

#define L_CTX 2048
#define B_SZ 4
#define DM 1024
#define NH 16
#define DH 64
#define M_ROWS (L_CTX * B_SZ)  // 8192
#define SCQ 0.04508422002778011f  // (1/32) * log2(e)

__device__ __forceinline__ void load_lds16(const void* g, void* l) {
  __builtin_amdgcn_global_load_lds(
      (const __attribute__((address_space(1))) unsigned int*)g,
      (__attribute__((address_space(3))) unsigned int*)l, 16, 0, 0);
}

__device__ __forceinline__ f32x4 mfma16(short8 a, short8 b, f32x4 c) {
  return __builtin_amdgcn_mfma_f32_16x16x32_bf16(
      __builtin_bit_cast(bf16x8, a), __builtin_bit_cast(bf16x8, b), c, 0, 0, 0);
}

__device__ __forceinline__ short tobf(float x) {
  return __builtin_bit_cast(short, __float2bfloat16(x));
}

// P >= 0, never NaN/inf: round-half-up truncation (2 VALU vs ~5 for RNE trick)
__device__ __forceinline__ short tobf_rh(float x) {
  unsigned u = __builtin_bit_cast(unsigned, x);
  return (short)((u + 0x8000u) >> 16);
}

#if __has_builtin(__builtin_amdgcn_exp2f)
#define EXP2(x) __builtin_amdgcn_exp2f(x)
#else
#define EXP2(x) exp2f(x)
#endif

#if __has_builtin(__builtin_amdgcn_rcpf)
#define RCP(x) __builtin_amdgcn_rcpf(x)
#else
#define RCP(x) (1.0f / (x))
#endif

#define TRRD(d, N) \
  asm volatile("ds_read_b64_tr_b16 %0, %1 offset:" #N : "=v"(d) : "v"(va))

__device__ __forceinline__ short8 mkv(u32x2 a, u32x2 b) {
  union { unsigned u[4]; short8 s; } x;
  x.u[0] = a.x; x.u[1] = a.y; x.u[2] = b.x; x.u[3] = b.y;
  return x.s;
}

// ---------------- cast f32 -> bf16 (q,k,v + 4 weights) ----------------
__global__ void cast_all(const float* __restrict__ q, const float* __restrict__ k,
                         const float* __restrict__ v, const float* __restrict__ wq,
                         const float* __restrict__ wk, const float* __restrict__ wv,
                         const float* __restrict__ wo, bf16* __restrict__ dq,
                         bf16* __restrict__ dk, bf16* __restrict__ dv,
                         bf16* __restrict__ dwq, bf16* __restrict__ dwk,
                         bf16* __restrict__ dwv, bf16* __restrict__ dwo) {
  unsigned u = blockIdx.x * 256u + threadIdx.x;
  const float* src;
  bf16* dst;
  unsigned off;
  if (u < 3145728u) {
    unsigned which = u >> 20;
    off = u & 1048575u;
    src = which == 0 ? q : which == 1 ? k : v;
    dst = which == 0 ? dq : which == 1 ? dk : dv;
  } else {
    unsigned w = u - 3145728u;
    unsigned which = w >> 17;
    off = w & 131071u;
    src = which == 0 ? wq : which == 1 ? wk : which == 2 ? wv : wo;
    dst = which == 0 ? dwq : which == 1 ? dwk : which == 2 ? dwv : dwo;
  }
  const float4* s4 = (const float4*)src + (size_t)off * 2;
  float4 a = s4[0], b = s4[1];
  union { bf16 h[8]; short8 s; } o;
  o.h[0] = __float2bfloat16(a.x); o.h[1] = __float2bfloat16(a.y);
  o.h[2] = __float2bfloat16(a.z); o.h[3] = __float2bfloat16(a.w);
  o.h[4] = __float2bfloat16(b.x); o.h[5] = __float2bfloat16(b.y);
  o.h[6] = __float2bfloat16(b.z); o.h[7] = __float2bfloat16(b.w);
  *(short8*)(dst + (size_t)off * 8) = o.s;
}

// ---- QKV GEMM: BM=128 x BN=256, 4 waves (wave tile 128x64), BK=32 ----
// Proven R4 schedule: TRIPLE-buffered LDS + counted vmcnt(6) (never drain
// in-loop). 12 ds_read_b128 per 32 MFMA per wave per K-step (half the
// LDS-read pressure of the 64x64 wave tile). LDS 3x24KB=72KB -> 2 blk/CU;
// grid 768 = 3 blocks/CU queued. Swizzle ((row>>1)&3) both sides: 2-way
// bank aliasing = free.
__global__ __launch_bounds__(256, 2) void gemm_qkv(
    const bf16* __restrict__ Aq, const bf16* __restrict__ Ak,
    const bf16* __restrict__ Av, const bf16* __restrict__ Wq,
    const bf16* __restrict__ Wk, const bf16* __restrict__ Wv,
    const float* __restrict__ bq, const float* __restrict__ bk,
    const float* __restrict__ bv, bf16* __restrict__ Oq, bf16* __restrict__ Ok,
    bf16* __restrict__ Ov) {
  const int K = DM;
  // grid 768 = 8 XCD * 96; per XCD: z(0..2) x 8 M-panels x 4 N-tiles
  int bid = blockIdx.x;
  int xcd = bid & 7, t_ = bid >> 3;             // t_ in [0,96)
  int z = t_ >> 5, rem = t_ & 31;               // z in [0,3)
  int bx = rem & 3, by = xcd * 8 + (rem >> 2);  // bx: N-tile(256), by: M-tile(128)
  const bf16* A = z == 0 ? Aq : z == 1 ? Ak : Av;
  const bf16* W = z == 0 ? Wq : z == 1 ? Wk : Wv;
  const float* bias = z == 0 ? bq : z == 1 ? bk : bv;
  bf16* Cout = z == 0 ? Oq : z == 1 ? Ok : Ov;
  const float scale = z == 0 ? SCQ : 1.0f;

  const int tid = threadIdx.x;
  const int wn = tid >> 6, ln = tid & 63, g = ln >> 4, lc = ln & 15;
  const int bm = by * 128, bn = bx * 256;

  __shared__ char smem[73728];  // 3 x (A[128][32] 8KB | B[256][32] 16KB)

  f32x4 acc[8][4] = {};

  auto stage = [&](int t, int s) {
    int kk = t * 32;
    char* base = smem + s * 24576;
#pragma unroll
    for (int l = 0; l < 2; ++l) {  // A: 512 x 16B
      int idx = l * 256 + tid;
      int rowi = idx >> 2, chunk = idx & 3;
      int cs = chunk ^ ((rowi >> 1) & 3);
      load_lds16(A + (size_t)(bm + rowi) * K + kk + cs * 8, base + idx * 16);
    }
#pragma unroll
    for (int l = 0; l < 4; ++l) {  // B: 1024 x 16B
      int idx = l * 256 + tid;
      int rowi = idx >> 2, chunk = idx & 3;
      int cs = chunk ^ ((rowi >> 1) & 3);
      load_lds16(W + (size_t)(bn + rowi) * K + kk + cs * 8,
                 base + 8192 + idx * 16);
    }
  };

  stage(0, 0);
  stage(1, 1);
  asm volatile("s_waitcnt vmcnt(6)" ::: "memory");  // tile 0 resident
  __syncthreads();

#pragma unroll
  for (int t = 0; t < 32; ++t) {
    if (t + 2 < 32) stage(t + 2, (t + 2) % 3);
    const char* As = smem + (t % 3) * 24576;
    const char* Bs = As + 8192;
    short8 af[8], bfr[4];
#pragma unroll
    for (int m = 0; m < 8; ++m) {
      int row = m * 16 + lc;
      af[m] = *(const short8*)(As + row * 64 + ((g ^ ((row >> 1) & 3)) << 4));
    }
#pragma unroll
    for (int n = 0; n < 4; ++n) {
      int row = wn * 64 + n * 16 + lc;
      bfr[n] = *(const short8*)(Bs + row * 64 + ((g ^ ((row >> 1) & 3)) << 4));
    }
    __builtin_amdgcn_s_setprio(1);
#pragma unroll
    for (int m = 0; m < 8; ++m)
#pragma unroll
      for (int n = 0; n < 4; ++n) acc[m][n] = mfma16(af[m], bfr[n], acc[m][n]);
    __builtin_amdgcn_s_setprio(0);
    if (t + 2 < 32)
      asm volatile("s_waitcnt vmcnt(6)" ::: "memory");  // t+1 resident, t+2 flying
    else
      asm volatile("s_waitcnt vmcnt(0)" ::: "memory");
    __syncthreads();
  }

  // epilogue: per-head layout [b][h][l][64]
#pragma unroll
  for (int n = 0; n < 4; ++n) {
    int col = bn + wn * 64 + n * 16 + lc;
    float bv = bias[col];
    int h = col >> 6, d = col & 63;
#pragma unroll
    for (int m = 0; m < 8; ++m) {
      int row0 = bm + m * 16 + g * 4;
#pragma unroll
      for (int i = 0; i < 4; ++i) {
        int row = row0 + i;
        int l = row >> 2, b = row & 3;
        Cout[(((size_t)(b * NH + h)) * L_CTX + l) * DH + d] =
            __float2bfloat16((acc[m][n][i] + bv) * scale);
      }
    }
  }
}

// ---------------- gemm_out: proven 128^2 body (fixed swizzle) ----------------
__global__ __launch_bounds__(256, 3) void gemm_out(const bf16* __restrict__ A,
                                                   const bf16* __restrict__ Bw,
                                                   const float* __restrict__ bias,
                                                   float* __restrict__ Cout) {
  const int K = DM, N = DM;
  int bid = blockIdx.x;
  int xcd = bid & 7, t_ = bid >> 3;
  int u = t_ >> 3, bxi = t_ & 7;
  int byi = xcd * 8 + u;
  const int tid = threadIdx.x;
  const int wv = tid >> 6, ln = tid & 63, g = ln >> 4, lc = ln & 15;
  const int wr = wv >> 1, wc = wv & 1;
  const int bm = byi * 128, bn = bxi * 128;

  __shared__ char smem[49152];  // 3 x (As 8KB | Bs 8KB)

  f32x4 acc[4][4] = {};

  const int srow = tid >> 2, sc_ = tid & 3;
  auto stage = [&](int t, int s) {
    int kk = t * 32;
#pragma unroll
    for (int i = 0; i < 2; ++i) {
      int row = i * 64 + srow;
      int cs = sc_ ^ ((row >> 1) & 3);
      load_lds16(A + (size_t)(bm + row) * K + kk + cs * 8,
                 smem + s * 16384 + i * 4096 + wv * 1024);
      load_lds16(Bw + (size_t)(bn + row) * K + kk + cs * 8,
                 smem + s * 16384 + 8192 + i * 4096 + wv * 1024);
    }
  };

  stage(0, 0);
  stage(1, 1);
  asm volatile("s_waitcnt vmcnt(4)" ::: "memory");
  __syncthreads();

#pragma unroll
  for (int t = 0; t < 32; ++t) {
    if (t + 2 < 32) stage(t + 2, (t + 2) % 3);
    const char* As = smem + (t % 3) * 16384;
    const char* Bs = As + 8192;
    short8 af[4], bfr[4];
#pragma unroll
    for (int m = 0; m < 4; ++m) {
      int row = wr * 64 + m * 16 + lc;
      af[m] = *(const short8*)(As + row * 64 + ((g ^ ((row >> 1) & 3)) << 4));
    }
#pragma unroll
    for (int n = 0; n < 4; ++n) {
      int row = wc * 64 + n * 16 + lc;
      bfr[n] = *(const short8*)(Bs + row * 64 + ((g ^ ((row >> 1) & 3)) << 4));
    }
    __builtin_amdgcn_s_setprio(1);
#pragma unroll
    for (int m = 0; m < 4; ++m)
#pragma unroll
      for (int n = 0; n < 4; ++n) acc[m][n] = mfma16(af[m], bfr[n], acc[m][n]);
    __builtin_amdgcn_s_setprio(0);
    if (t + 2 < 32)
      asm volatile("s_waitcnt vmcnt(4)" ::: "memory");
    else
      asm volatile("s_waitcnt vmcnt(0)" ::: "memory");
    __syncthreads();
  }

#pragma unroll
  for (int n = 0; n < 4; ++n) {
    int col = bn + wc * 64 + n * 16 + lc;
    float bv = bias[col];
#pragma unroll
    for (int m = 0; m < 4; ++m) {
      int row0 = bm + wr * 64 + m * 16 + g * 4;
#pragma unroll
      for (int i = 0; i < 4; ++i) {
        int row = row0 + i;
        Cout[(size_t)row * N + col] = acc[m][n][i] + bv;
      }
    }
  }
}

// ---------------- flash attention v7 (unchanged, proven) ----------------
__global__ __launch_bounds__(256, 4) void attn_fwd7(const bf16* __restrict__ Q,
                                                    const bf16* __restrict__ K,
                                                    const bf16* __restrict__ V,
                                                    bf16* __restrict__ O) {
  const int tid = threadIdx.x, w = tid >> 6, ln = tid & 63, g = ln >> 4,
            lc = ln & 15;
  const int bid = blockIdx.x;
  const int j = bid >> 3;
  const int bh = (bid & 7) * 8 + (j & 7);  // 8 heads per XCD -> K/V L2-local
  const int pa = j >> 3;
  const int b = bh >> 4, h = bh & 15;

  __shared__ char smem[32768];  // K 2x8KB @0, V 2x8KB @16384
  const bf16* Qh = Q + (size_t)bh * L_CTX * DH;
  const bf16* Kh = K + (size_t)bh * L_CTX * DH;
  const bf16* Vh = V + (size_t)bh * L_CTX * DH;

  const unsigned vbase =
      (unsigned)(size_t)(__attribute__((address_space(3))) char*)(smem + 16384);

  const int krow_l = ln >> 3, kslot = ln & 7;
  const int vr = (ln & 7) >> 1, vc0 = (ln & 1) * 8;

  const short ONEBF = 0x3F80;  // bf16 1.0
  const short8 ones8 = {ONEBF, ONEBF, ONEBF, ONEBF, ONEBF, ONEBF, ONEBF, ONEBF};

#pragma unroll 1
  for (int rep = 0; rep < 2; ++rep) {
    const int qt = rep ? (31 - pa) : pa;
    const int qb = qt * 64 + w * 16;
    const int nt = qt + 1;

    short8 qf0 = *(const short8*)(Qh + (qb + lc) * DH + g * 8);
    short8 qf1 = *(const short8*)(Qh + (qb + lc) * DH + 32 + g * 8);

    f32x4 oacc[4] = {};
    f32x4 lacc = {};  // rowsum accumulator

    auto stage = [&](int t, int s) {
#pragma unroll
      for (int i = 0; i < 2; ++i) {  // K: 64 rows x 128B, source-swizzled
        int row = (i * 4 + w) * 8 + krow_l;
        int slot = kslot ^ (row & 7);
        load_lds16(Kh + (size_t)(t * 64 + row) * DH + slot * 8,
                   smem + s * 8192 + (i * 4 + w) * 1024);
      }
#pragma unroll
      for (int Lg = 0; Lg < 2; ++Lg) {  // V: subtiled perm via source addr
        int blk = w * 8 + Lg * 32 + krow_l;
        int sq = blk & 15, dt = blk >> 4;
        load_lds16(Vh + (size_t)(t * 64 + sq * 4 + vr) * DH + dt * 16 + vc0,
                   smem + 16384 + s * 8192 + Lg * 4096 + w * 1024);
      }
    };

    int sel = 0;
    stage(0, 0);
    asm volatile("s_waitcnt vmcnt(0)" ::: "memory");
    __syncthreads();

    for (int t = 0; t < nt; ++t) {
      if (t + 1 < nt) stage(t + 1, sel ^ 1);

      // ---- QK^T (swapped: S^T = K*Qscaled) ----
      const char* Kl = smem + sel * 8192;
      f32x4 st[4] = {};
      __builtin_amdgcn_s_setprio(1);
#pragma unroll
      for (int tt = 0; tt < 4; ++tt) {
        int row = tt * 16 + lc, sw = lc & 7;
        short8 kf0 = *(const short8*)(Kl + row * 128 + ((g ^ sw) << 4));
        short8 kf1 = *(const short8*)(Kl + row * 128 + (((4 + g) ^ sw) << 4));
        st[tt] = mfma16(kf0, qf0, st[tt]);
        st[tt] = mfma16(kf1, qf1, st[tt]);
      }
      __builtin_amdgcn_s_setprio(0);

      // ---- issue V transpose reads early ----
      unsigned va = vbase + sel * 8192 + ln * 8;
      u32x2 t0a, t0b, t1a, t1b, t2a, t2b, t3a, t3b;
      u32x2 s0a, s0b, s1a, s1b, s2a, s2b, s3a, s3b;
      TRRD(t0a, 0);    TRRD(t0b, 512);
      TRRD(t1a, 2048); TRRD(t1b, 2560);
      TRRD(t2a, 4096); TRRD(t2b, 4608);
      TRRD(t3a, 6144); TRRD(t3b, 6656);
      TRRD(s0a, 1024); TRRD(s0b, 1536);
      TRRD(s1a, 3072); TRRD(s1b, 3584);
      TRRD(s2a, 5120); TRRD(s2b, 5632);
      TRRD(s3a, 7168); TRRD(s3b, 7680);

      // ---- causal mask: only last tile touches the diagonal ----
      if (t == nt - 1) {
        int qrel = w * 16 + lc;
#pragma unroll
        for (int tt = 0; tt < 4; ++tt)
#pragma unroll
          for (int i = 0; i < 4; ++i)
            if (tt * 16 + g * 4 + i > qrel) st[tt][i] = -__builtin_inff();
      }

      // ---- P = exp2(z) single-inst, pack round-half-up ----
      union { short s[8]; short8 v; } p0, p1;
#pragma unroll
      for (int i = 0; i < 4; ++i) {
        p0.s[i]     = tobf_rh(EXP2(st[0][i]));
        p0.s[4 + i] = tobf_rh(EXP2(st[1][i]));
        p1.s[i]     = tobf_rh(EXP2(st[2][i]));
        p1.s[4 + i] = tobf_rh(EXP2(st[3][i]));
      }

      // ---- PV + rowsum-by-MFMA ----
      asm volatile("s_waitcnt lgkmcnt(0)" ::: "memory");
      __builtin_amdgcn_sched_barrier(0);
      __builtin_amdgcn_s_setprio(1);
      oacc[0] = mfma16(p0.v, mkv(t0a, t0b), oacc[0]);
      oacc[1] = mfma16(p0.v, mkv(t1a, t1b), oacc[1]);
      oacc[2] = mfma16(p0.v, mkv(t2a, t2b), oacc[2]);
      oacc[3] = mfma16(p0.v, mkv(t3a, t3b), oacc[3]);
      lacc = mfma16(p0.v, ones8, lacc);
      oacc[0] = mfma16(p1.v, mkv(s0a, s0b), oacc[0]);
      oacc[1] = mfma16(p1.v, mkv(s1a, s1b), oacc[1]);
      oacc[2] = mfma16(p1.v, mkv(s2a, s2b), oacc[2]);
      oacc[3] = mfma16(p1.v, mkv(s3a, s3b), oacc[3]);
      lacc = mfma16(p1.v, ones8, lacc);
      __builtin_amdgcn_s_setprio(0);

      asm volatile("s_waitcnt vmcnt(0)" ::: "memory");
      __syncthreads();
      sel ^= 1;
    }

    // ---- epilogue ----
    float li[4];
#pragma unroll
    for (int i = 0; i < 4; ++i) li[i] = RCP(lacc[i]);
#pragma unroll
    for (int n = 0; n < 4; ++n)
#pragma unroll
      for (int i = 0; i < 4; ++i) {
        int qi = qb + g * 4 + i;
        int col = h * DH + n * 16 + lc;
        O[((size_t)qi * B_SZ + b) * DM + col] =
            __float2bfloat16(oacc[n][i] * li[i]);
      }
  }
}

// ---------------- launch ----------------
extern "C" void kernel_launch(void* const* d_in, const int* in_sizes, int n_in,
                              void* d_out, int out_size, void* d_ws, size_t ws_size,
                              hipStream_t stream) {
  const float* q = (const float*)d_in[0];
  const float* k = (const float*)d_in[1];
  const float* v = (const float*)d_in[2];
  const float* wq = (const float*)d_in[4];
  const float* bq = (const float*)d_in[5];
  const float* wk = (const float*)d_in[6];
  const float* bk = (const float*)d_in[7];
  const float* wv = (const float*)d_in[8];
  const float* bv = (const float*)d_in[9];
  const float* wo = (const float*)d_in[10];
  const float* bo = (const float*)d_in[11];

  if (ws_size < 125829120u) return;

  char* ws = (char*)d_ws;
  bf16* qb_ = (bf16*)(ws);
  bf16* kb_ = (bf16*)(ws + 16777216);
  bf16* vb_ = (bf16*)(ws + 33554432);
  bf16* wqb = (bf16*)(ws + 50331648);
  bf16* wkb = (bf16*)(ws + 52428800);
  bf16* wvb = (bf16*)(ws + 54525952);
  bf16* wob = (bf16*)(ws + 56623104);
  bf16* Qp = (bf16*)(ws + 58720256);
  bf16* Kp = (bf16*)(ws + 75497472);
  bf16* Vp = (bf16*)(ws + 92274688);
  bf16* Ob = (bf16*)(ws + 109051904);

  cast_all<<<14336, 256, 0, stream>>>(q, k, v, wq, wk, wv, wo, qb_, kb_, vb_, wqb,
                                      wkb, wvb, wob);
  gemm_qkv<<<768, 256, 0, stream>>>(qb_, kb_, vb_, wqb, wkb, wvb, bq, bk, bv,
                                    Qp, Kp, Vp);
  attn_fwd7<<<1024, 256, 0, stream>>>(Qp, Kp, Vp, Ob);
  gemm_out<<<512, 256, 0, stream>>>(Ob, wob, bo, (float*)d_out);
}